// Round 6
// baseline (297.952 us; speedup 1.0000x reference)
//
#include <hip/hip_runtime.h>
#include <hip/hip_bf16.h>
#include <math.h>

// Problem constants
#define BATCH 4
#define SEQ   2048
#define HID   768
#define INTER 1536
#define DK    128
#define NTOT  3200      // 2*INTER + DK
#define NTOTP 3328      // padded to 13*256 for 256-wide gemm1 tiles
#define MROWS 8192      // BATCH*SEQ
#define LN512 6.2383246250395075f

typedef _Float16 half8   __attribute__((ext_vector_type(8)));
typedef _Float16 half4   __attribute__((ext_vector_type(4)));
typedef float    floatx4 __attribute__((ext_vector_type(4)));
typedef float    floatx16 __attribute__((ext_vector_type(16)));

typedef const __attribute__((address_space(1))) unsigned int* gas1_t;
typedef __attribute__((address_space(3))) unsigned int* las3_t;

static __device__ __forceinline__ void load16(const _Float16* g, _Float16* l) {
    __builtin_amdgcn_global_load_lds((gas1_t)g, (las3_t)l, 16, 0, 0);
}
#define WAIT_VM(N)    asm volatile("s_waitcnt vmcnt(" #N ")" ::: "memory")
#define WAIT_LGKM0()  asm volatile("s_waitcnt lgkmcnt(0)" ::: "memory")
#define BARRIER_RAW() asm volatile("s_barrier" ::: "memory")
#define GLOAD16(dst, ptr) \
    asm volatile("global_load_dwordx4 %0, %1, off" : "=v"(dst) : "v"(ptr) : "memory")

// ---------------------------------------------------------------- merged prep kernel
__global__ __launch_bounds__(256) void prep_kernel(
    const float* __restrict__ H, _Float16* __restrict__ Hb,
    const float* __restrict__ Wi, _Float16* __restrict__ WiT,
    const float* __restrict__ Wo, _Float16* __restrict__ WoT,
    const int* __restrict__ mask, float* __restrict__ scales)
{
    __shared__ _Float16 tile[32][33];
    __shared__ int sh[256];
    const int bid = blockIdx.x, tid = threadIdx.x;
    if (bid < 3072) {
        const int i = (bid * 256 + tid) * 8;
        float4 a = *reinterpret_cast<const float4*>(H + i);
        float4 b = *reinterpret_cast<const float4*>(H + i + 4);
        half8 h = {(_Float16)a.x, (_Float16)a.y, (_Float16)a.z, (_Float16)a.w,
                   (_Float16)b.x, (_Float16)b.y, (_Float16)b.z, (_Float16)b.w};
        *reinterpret_cast<half8*>(Hb + i) = h;
    } else if (bid < 3072 + 2496) {
        const int l = bid - 3072;
        const int c0 = (l % 104) * 32, r0 = (l / 104) * 32;
        const int tx = tid & 31, ty = tid >> 5;
#pragma unroll
        for (int j = 0; j < 32; j += 8)
            tile[tx][ty + j] = (c0 + tx < NTOT)
                ? (_Float16)Wi[(size_t)(r0 + ty + j) * NTOT + c0 + tx]
                : (_Float16)0.0f;
        __syncthreads();
#pragma unroll
        for (int j = 0; j < 32; j += 8)
            WiT[(size_t)(c0 + ty + j) * HID + r0 + tx] = tile[ty + j][tx];
    } else if (bid < 3072 + 2496 + 1152) {
        const int l = bid - (3072 + 2496);
        const int c0 = (l % 24) * 32, r0 = (l / 24) * 32;
        const int tx = tid & 31, ty = tid >> 5;
#pragma unroll
        for (int j = 0; j < 32; j += 8)
            tile[tx][ty + j] = (_Float16)Wo[(size_t)(r0 + ty + j) * HID + c0 + tx];
        __syncthreads();
#pragma unroll
        for (int j = 0; j < 32; j += 8)
            WoT[(size_t)(c0 + ty + j) * INTER + r0 + tx] = tile[ty + j][tx];
    } else {
        const int b = bid - (3072 + 2496 + 1152);
        int s = 0;
        for (int i = tid; i < SEQ; i += 256) s += mask[b * SEQ + i];
        sh[tid] = s;
        __syncthreads();
        for (int off = 128; off > 0; off >>= 1) {
            if (tid < off) sh[tid] += sh[tid + off];
            __syncthreads();
        }
        if (tid == 0) scales[b] = logf((float)sh[0]) / LN512;
    }
}

// ---------------------------------------------------------------- shared tile ctx (256-thread kernels)
struct TileCtx {
    int tid, wave, lane, quad, l16, l31, half, wm, wn, c0, c1;
};
static __device__ __forceinline__ TileCtx make_ctx() {
    TileCtx t;
    t.tid = threadIdx.x;
    t.wave = t.tid >> 6; t.lane = t.tid & 63;
    t.quad = t.lane >> 4; t.l16 = t.lane & 15;
    t.l31 = t.lane & 31;  t.half = t.lane >> 5;
    t.wm = (t.wave & 1) * 64;
    t.wn = (t.wave >> 1) * 64;
    t.c0 = t.tid;
    t.c1 = t.tid + 256;
    return t;
}

// ================================================================ mainloop RO32: 32x32x16, read-ahead pipelined (gemm2)
// 4 slots x 16KB; per iter: {stage(k+2); vmcnt(4); barrier; ds_read frags(k+1);
// MFMA(k) from last iter's regs; lgkmcnt(0)}. lgkm0-before-barrier makes slot
// reuse race-free (reads of slot s done before barrier s+1; overwrite issues
// after barrier s+1).
#define RO32_READ(FR, SLOT) do {                                               \
    const _Float16* Ab_ = smem + (SLOT) * 8192;                                \
    const _Float16* Bb_ = Ab_ + 4096;                                          \
    _Pragma("unroll")                                                          \
    for (int mt = 0; mt < 2; ++mt)                                             \
        _Pragma("unroll")                                                      \
        for (int h = 0; h < 2; ++h)                                            \
            FR##a[mt][h] = *reinterpret_cast<const half8*>(                    \
                Ab_ + (t.wm + mt * 32 + t.l31) * 32 + (((h * 2 + t.half) ^ fsw) * 8)); \
    _Pragma("unroll")                                                          \
    for (int nt = 0; nt < 2; ++nt)                                             \
        _Pragma("unroll")                                                      \
        for (int h = 0; h < 2; ++h)                                            \
            FR##b[nt][h] = *reinterpret_cast<const half8*>(                    \
                Bb_ + (t.wn + nt * 32 + t.l31) * 32 + (((h * 2 + t.half) ^ fsw) * 8)); \
} while (0)

#define RO32_MMA(FR) do {                                                      \
    __builtin_amdgcn_s_setprio(1);                                             \
    _Pragma("unroll")                                                          \
    for (int h = 0; h < 2; ++h)                                                \
        _Pragma("unroll")                                                      \
        for (int mt = 0; mt < 2; ++mt)                                         \
            _Pragma("unroll")                                                  \
            for (int nt = 0; nt < 2; ++nt)                                     \
                acc[mt][nt] = __builtin_amdgcn_mfma_f32_32x32x16_f16(          \
                    FR##a[mt][h], FR##b[nt][h], acc[mt][nt], 0, 0, 0);         \
    __builtin_amdgcn_s_setprio(0);                                             \
} while (0)

#define RO32_STAGE(K) do {                                                     \
    _Float16* ld_ = smem2 + ((K) & 3) * 8192 + t.c0 * 8;                       \
    const int ko_ = (K) << 5;                                                  \
    load16(a0 + ko_, ld_);        load16(a1 + ko_, ld_ + 2048);                \
    load16(b0 + ko_, ld_ + 4096); load16(b1 + ko_, ld_ + 6144);                \
} while (0)

#define RO32_ITER(K, CUR, NXT) do {                                            \
    if ((K) + 2 < nIter) RO32_STAGE((K) + 2);                                  \
    if ((K) + 2 < nIter)      { WAIT_VM(4); }                                  \
    else if ((K) + 1 < nIter) { WAIT_VM(0); }                                  \
    else                      { WAIT_VM(0); }                                  \
    __builtin_amdgcn_sched_barrier(0);                                         \
    BARRIER_RAW();                                                             \
    if ((K) + 1 < nIter) RO32_READ(NXT, ((K) + 1) & 3);                        \
    RO32_MMA(CUR);                                                             \
    WAIT_LGKM0();                                                              \
} while (0)

static __device__ __forceinline__ void gemm_mainloop_ro32(
    const TileCtx& t,
    const _Float16* __restrict__ Ag, int lda,
    const _Float16* __restrict__ Bg, int ldb,
    int K, _Float16* smem, floatx16 acc[2][2])
{
    const int r0i = t.c0 >> 2, s0 = (((r0i >> 1) ^ (r0i >> 3)) & 3);
    const int r1i = t.c1 >> 2, s1 = (((r1i >> 1) ^ (r1i >> 3)) & 3);
    const _Float16* a0 = Ag + (size_t)r0i * lda + ((t.c0 & 3) ^ s0) * 8;
    const _Float16* a1 = Ag + (size_t)r1i * lda + ((t.c1 & 3) ^ s1) * 8;
    const _Float16* b0 = Bg + (size_t)r0i * ldb + ((t.c0 & 3) ^ s0) * 8;
    const _Float16* b1 = Bg + (size_t)r1i * ldb + ((t.c1 & 3) ^ s1) * 8;
    _Float16* smem2 = smem;
    const int nIter = K >> 5;
    const int fsw = ((t.l31 >> 1) ^ (t.l31 >> 3)) & 3;

    half8 pa[2][2], pb[2][2], qa[2][2], qb[2][2];   // ping-pong frag sets

    RO32_STAGE(0);
    RO32_STAGE(1);
    WAIT_VM(4);        // drains S0 (leaves S1)
    BARRIER_RAW();
    RO32_READ(p, 0);

    for (int k = 0; k < nIter; k += 2) {
        RO32_ITER(k,     p, q);
        RO32_ITER(k + 1, q, p);
    }
}

// ---------------------------------------------------------------- GEMM1: silu(H@Wi) -> u, vT, q, k
// R6: read-ahead pipelined version of the R2 schedule: per K-tile
// {stage(t+3); vmcnt; barrier; ds_read frags(t+1); MFMA(t); lgkm0}.
__global__ __launch_bounds__(512, 2) void gemm1_kernel(
    const _Float16* __restrict__ Hb, const _Float16* __restrict__ WiT,
    const float* __restrict__ qg, const float* __restrict__ kg,
    _Float16* __restrict__ u, _Float16* __restrict__ vT,
    _Float16* __restrict__ q, _Float16* __restrict__ k)
{
    __shared__ _Float16 smem[65536];   // 4 slots x 32KB (A 16KB + B 16KB)
    const int tid = threadIdx.x;
    const int lane = tid & 63, wave = tid >> 6;
    const int quad = lane >> 4, l16 = lane & 15;
    const int wm = wave >> 2, wn = wave & 3;          // 2M x 4N waves

    const int f = blockIdx.x;
    const int xcd = f & 7, i = f >> 3;                // i: 0..51
    const int m0 = (xcd * 4 + (i & 3)) * 256;
    const int ntile = i >> 2;                         // 0..12
    const int n0 = ntile * 256;

    const _Float16* Ag = Hb  + (size_t)m0 * HID;
    const _Float16* Bg = WiT + (size_t)n0 * HID;

    const int rA = tid >> 2;
    const int csw = ((tid & 3) ^ ((rA >> 1) & 3)) * 8;
    const _Float16* pa0 = Ag + (size_t)rA * HID + csw;
    const _Float16* pa1 = pa0 + (size_t)128 * HID;
    const _Float16* pb0 = Bg + (size_t)rA * HID + csw;
    const _Float16* pb1 = pb0 + (size_t)128 * HID;

    const int sw8 = (l16 >> 1) & 3;
    const int qs  = (quad ^ sw8) * 8;
    const int aoff = (wm * 128 + l16) * 32 + qs;
    const int boff = 8192 + (wn * 64 + l16) * 32 + qs;

    floatx4 acc[8][4] = {};
    half8 pa_[8], pb_[4], qa_[8], qb_[4];   // ping-pong frag sets

    const int nKt = HID / 32;   // 24

#define G1_STAGE(T) do {                                                       \
        _Float16* ld_ = smem + ((T) & 3) * 16384 + tid * 8;                    \
        const int ko_ = (T) << 5;                                              \
        load16(pa0 + ko_, ld_);        load16(pa1 + ko_, ld_ + 4096);          \
        load16(pb0 + ko_, ld_ + 8192); load16(pb1 + ko_, ld_ + 12288);         \
    } while (0)

#define G1_READ(AF, BF, SLOT) do {                                             \
        const _Float16* sl_ = smem + (SLOT) * 16384;                           \
        _Pragma("unroll")                                                      \
        for (int mt = 0; mt < 8; ++mt)                                         \
            AF[mt] = *reinterpret_cast<const half8*>(sl_ + aoff + mt * 512);   \
        _Pragma("unroll")                                                      \
        for (int nt = 0; nt < 4; ++nt)                                         \
            BF[nt] = *reinterpret_cast<const half8*>(sl_ + boff + nt * 512);   \
    } while (0)

#define G1_ITER(T, AFC, BFC, AFN, BFN) do {                                    \
        if ((T) + 3 < nKt) G1_STAGE((T) + 3);                                  \
        if ((T) + 3 < nKt)      { WAIT_VM(8); }                                \
        else if ((T) + 2 < nKt) { WAIT_VM(4); }                                \
        else                    { WAIT_VM(0); }                                \
        __builtin_amdgcn_sched_barrier(0);                                     \
        BARRIER_RAW();                                                         \
        if ((T) + 1 < nKt) G1_READ(AFN, BFN, ((T) + 1) & 3);                   \
        __builtin_amdgcn_s_setprio(1);                                         \
        _Pragma("unroll")                                                      \
        for (int mt = 0; mt < 8; ++mt)                                         \
            _Pragma("unroll")                                                  \
            for (int nt = 0; nt < 4; ++nt)                                     \
                acc[mt][nt] = __builtin_amdgcn_mfma_f32_16x16x32_f16(          \
                    AFC[mt], BFC[nt], acc[mt][nt], 0, 0, 0);                   \
        __builtin_amdgcn_s_setprio(0);                                         \
        WAIT_LGKM0();                                                          \
    } while (0)

    // prologue: stage tiles 0..2 into slots 0..2; read tile 0 frags
    G1_STAGE(0); G1_STAGE(1); G1_STAGE(2);
    WAIT_VM(8);        // drains S0 (leaves S1,S2)
    BARRIER_RAW();
    G1_READ(pa_, pb_, 0);

    for (int t = 0; t < nKt; t += 2) {
        G1_ITER(t,     pa_, pb_, qa_, qb_);
        G1_ITER(t + 1, qa_, qb_, pa_, pb_);
    }
    __syncthreads();

    // ---------------- epilogue: silu + region-specific stores
    if (ntile < 6) {
#pragma unroll
        for (int mt = 0; mt < 8; ++mt) {
#pragma unroll
            for (int nt = 0; nt < 4; ++nt) {
                const int col = n0 + wn * 64 + nt * 16 + l16;
#pragma unroll
                for (int i2 = 0; i2 < 4; ++i2) {
                    const int row = m0 + wm * 128 + mt * 16 + quad * 4 + i2;
                    float x = acc[mt][nt][i2];
                    float y = x / (1.0f + __expf(-x));
                    u[(size_t)row * INTER + col] = (_Float16)y;
                }
            }
        }
    } else if (ntile < 12) {
        const int bb = m0 >> 11, sloc = m0 & (SEQ - 1), cI = n0 - INTER;
#pragma unroll
        for (int mt = 0; mt < 8; ++mt) {
#pragma unroll
            for (int nt = 0; nt < 4; ++nt) {
                const int cl  = wn * 64 + nt * 16 + l16;
                const int rl0 = wm * 128 + mt * 16 + quad * 4;
                half4 pk;
#pragma unroll
                for (int i2 = 0; i2 < 4; ++i2) {
                    float x = acc[mt][nt][i2];
                    pk[i2] = (_Float16)(x / (1.0f + __expf(-x)));
                }
                *reinterpret_cast<half4*>(smem + cl * 256 + (rl0 ^ ((cl & 31) << 3))) = pk;
            }
        }
        __syncthreads();
#pragma unroll
        for (int p = 0; p < 16; ++p) {
            const int chunk = p * 512 + tid;
            const int cl = chunk >> 5, scn = chunk & 31;
            half8 v = *reinterpret_cast<const half8*>(smem + cl * 256 + ((scn ^ (cl & 31)) << 3));
            *reinterpret_cast<half8*>(vT + ((size_t)bb * INTER + cI + cl) * SEQ + sloc + scn * 8) = v;
        }
    } else {
        if (wn < 2) {
#pragma unroll
            for (int mt = 0; mt < 8; ++mt) {
#pragma unroll
                for (int nt = 0; nt < 4; ++nt) {
                    const int cq = wn * 64 + nt * 16 + l16;
                    const float qgv = qg[cq], kgv = kg[cq];
#pragma unroll
                    for (int i2 = 0; i2 < 4; ++i2) {
                        const int row = m0 + wm * 128 + mt * 16 + quad * 4 + i2;
                        float x = acc[mt][nt][i2];
                        float y = x / (1.0f + __expf(-x));
                        q[(size_t)row * DK + cq] = (_Float16)(y * qgv);
                        k[(size_t)row * DK + cq] = (_Float16)(y * kgv);
                    }
                }
            }
        }
    }
}

// ---------------------------------------------------------------- scores + softmax -> P_frag (f16)
__global__ __launch_bounds__(256) void scores_kernel(
    const _Float16* __restrict__ q, const _Float16* __restrict__ k,
    const int* __restrict__ mask, const float* __restrict__ scales,
    _Float16* __restrict__ P)
{
    __shared__ _Float16 ps[16 * 2056];
    __shared__ float redmax[4][16];
    __shared__ float redsum[4][16];
    const int f = blockIdx.x;
    const int xcd = f & 7, i = f >> 3;          // i: 0..63
    const int b = xcd >> 1;
    const int m0 = ((xcd & 1) * 64 + i) * 16;
    const int tid = threadIdx.x;
    const int wave = tid >> 6, lane = tid & 63, quad = lane >> 4, l16 = lane & 15;
    const float scale = scales[b];

    half8 aq[4];
    const _Float16* qrow = q + (b * SEQ + m0 + l16) * DK + quad * 8;
#pragma unroll
    for (int kk = 0; kk < 4; ++kk) aq[kk] = *reinterpret_cast<const half8*>(qrow + kk * 32);

    floatx4 sc[32];
#pragma unroll
    for (int nt = 0; nt < 32; ++nt) {
        int n0 = nt * 64 + wave * 16;
        const _Float16* krow = k + (b * SEQ + n0 + l16) * DK + quad * 8;
        floatx4 acc = {};
#pragma unroll
        for (int kk = 0; kk < 4; ++kk) {
            half8 bq = *reinterpret_cast<const half8*>(krow + kk * 32);
            acc = __builtin_amdgcn_mfma_f32_16x16x32_f16(aq[kk], bq, acc, 0, 0, 0);
        }
        sc[nt] = acc;
    }

    const float rs = 0.08838834764831845f * scale;
    const float mval = -1e12f * scale;
    float rmax[4] = {-3.4e38f, -3.4e38f, -3.4e38f, -3.4e38f};
#pragma unroll
    for (int nt = 0; nt < 32; ++nt) {
        int ncol = nt * 64 + wave * 16 + l16;
        bool mok = mask[b * SEQ + ncol] != 0;
#pragma unroll
        for (int i2 = 0; i2 < 4; ++i2) {
            float s = mok ? sc[nt][i2] * rs : mval;
            sc[nt][i2] = s;
            rmax[i2] = fmaxf(rmax[i2], s);
        }
    }
#pragma unroll
    for (int i2 = 0; i2 < 4; ++i2) {
#pragma unroll
        for (int off = 1; off < 16; off <<= 1)
            rmax[i2] = fmaxf(rmax[i2], __shfl_xor(rmax[i2], off, 64));
    }
    if (l16 == 0) {
#pragma unroll
        for (int i2 = 0; i2 < 4; ++i2) redmax[wave][quad * 4 + i2] = rmax[i2];
    }
    __syncthreads();
#pragma unroll
    for (int i2 = 0; i2 < 4; ++i2) {
        int r = quad * 4 + i2;
        rmax[i2] = fmaxf(fmaxf(redmax[0][r], redmax[1][r]), fmaxf(redmax[2][r], redmax[3][r]));
    }
    float rsum[4] = {0.f, 0.f, 0.f, 0.f};
#pragma unroll
    for (int nt = 0; nt < 32; ++nt) {
#pragma unroll
        for (int i2 = 0; i2 < 4; ++i2) {
            float e = __expf(sc[nt][i2] - rmax[i2]);
            sc[nt][i2] = e;
            rsum[i2] += e;
        }
    }
#pragma unroll
    for (int i2 = 0; i2 < 4; ++i2) {
#pragma unroll
        for (int off = 1; off < 16; off <<= 1) rsum[i2] += __shfl_xor(rsum[i2], off, 64);
    }
    if (l16 == 0) {
#pragma unroll
        for (int i2 = 0; i2 < 4; ++i2) redsum[wave][quad * 4 + i2] = rsum[i2];
    }
    __syncthreads();
#pragma unroll
    for (int i2 = 0; i2 < 4; ++i2) {
        int r = quad * 4 + i2;
        float tot = redsum[0][r] + redsum[1][r] + redsum[2][r] + redsum[3][r];
        float inv = 1.0f / tot;
#pragma unroll
        for (int nt = 0; nt < 32; ++nt) {
            int ncol = nt * 64 + wave * 16 + l16;
            ps[r * 2056 + ncol] = (_Float16)(sc[nt][i2] * inv);
        }
    }
    __syncthreads();
    _Float16* Pfb = P + (size_t)b * SEQ * SEQ;
#pragma unroll
    for (int p = 0; p < 16; ++p) {
        const int chunk = p * 256 + tid;
        const int row = chunk & 15, c8 = chunk >> 4;
        half8 v = *reinterpret_cast<const half8*>(ps + row * 2056 + c8 * 8);
        *reinterpret_cast<half8*>(Pfb + ((size_t)c8 * SEQ + m0 + row) * 8) = v;
    }
}

// ---------------------------------------------------------------- PV: u <- u .* (P @ v)
// R6: read-ahead pipelined. A (P_frag) global->VGPR ping-pong; B (vT) in 4 LDS
// slots x 8KB, stage-dist 2; per iter {gloadA(k+1); stageB(k+2); vmcnt(6);
// barrier; ds_read bf(k+1); MFMA(k); lgkm0}.
__global__ __launch_bounds__(256) void pv_kernel(
    const _Float16* __restrict__ Pf, const _Float16* __restrict__ vT,
    _Float16* __restrict__ u)
{
    __shared__ _Float16 smem[16384];   // 4 slots x 8KB (B only)
    TileCtx t = make_ctx();
    const int f = blockIdx.x;
    const int xcd = f & 7, i = f >> 3;
    const int b = i / 24, j = i % 24;
    const int m0 = (xcd * 2 + (j & 1)) * 128;
    const int n0 = (j >> 1) * 128;
    const _Float16* Pfb = Pf + (size_t)b * SEQ * SEQ;   // [256 chunks][2048 rows][8]
    const _Float16* vTb = vT + (size_t)b * INTER * SEQ;

    const int r0i = t.c0 >> 2, s0 = (((r0i >> 1) ^ (r0i >> 3)) & 3);
    const int r1i = t.c1 >> 2, s1 = (((r1i >> 1) ^ (r1i >> 3)) & 3);
    const _Float16* b0 = vTb + (size_t)(n0 + r0i) * SEQ + ((t.c0 & 3) ^ s0) * 8;
    const _Float16* b1 = vTb + (size_t)(n0 + r1i) * SEQ + ((t.c1 & 3) ^ s1) * 8;
    const int fsw = ((t.l31 >> 1) ^ (t.l31 >> 3)) & 3;

    const _Float16* pA0 = Pfb + (size_t)t.half * (SEQ * 8)
                        + (size_t)(m0 + t.wm + t.l31) * 8;
    const _Float16* pA1 = pA0 + 32 * 8;

    floatx16 acc[2][2] = {};
    half8 afA[2][2], afB[2][2], bfA[2][2], bfB[2][2];

#define PV_GLOADA(AF, K) do {                                                  \
        const size_t co_ = (size_t)(K) * 4 * (SEQ * 8);                        \
        GLOAD16(AF[0][0], pA0 + co_);                                          \
        GLOAD16(AF[0][1], pA0 + co_ + 2 * (SEQ * 8));                          \
        GLOAD16(AF[1][0], pA1 + co_);                                          \
        GLOAD16(AF[1][1], pA1 + co_ + 2 * (SEQ * 8));                          \
    } while (0)

#define PV_STAGEB(K) do {                                                      \
        _Float16* ld_ = smem + ((K) & 3) * 4096 + t.c0 * 8;                    \
        const int ko_ = (K) << 5;                                              \
        load16(b0 + ko_, ld_);                                                 \
        load16(b1 + ko_, ld_ + 2048);                                          \
    } while (0)

#define PV_READB(BF, SLOT) do {                                                \
        const _Float16* Bb_ = smem + (SLOT) * 4096;                            \
        _Pragma("unroll")                                                      \
        for (int nt = 0; nt < 2; ++nt)                                         \
            _Pragma("unroll")                                                  \
            for (int h = 0; h < 2; ++h)                                        \
                BF[nt][h] = *reinterpret_cast<const half8*>(                   \
                    Bb_ + (t.wn + nt * 32 + t.l31) * 32 + (((h * 2 + t.half) ^ fsw) * 8)); \
    } while (0)

#define PV_ITER(K, AFC, BFC, AFN, BFN) do {                                    \
        if ((K) + 1 < 64) PV_GLOADA(AFN, (K) + 1);                             \
        if ((K) + 2 < 64) PV_STAGEB((K) + 2);                                  \
        if ((K) + 2 < 64)      { WAIT_VM(6); }                                 \
        else if ((K) + 1 < 64) { WAIT_VM(4); }                                 \
        else                   { WAIT_VM(0); }                                 \
        __builtin_amdgcn_sched_barrier(0);                                     \
        BARRIER_RAW();                                                         \
        if ((K) + 1 < 64) PV_READB(BFN, ((K) + 1) & 3);                        \
        __builtin_amdgcn_s_setprio(1);                                         \
        _Pragma("unroll")                                                      \
        for (int h = 0; h < 2; ++h)                                            \
            _Pragma("unroll")                                                  \
            for (int mt = 0; mt < 2; ++mt)                                     \
                _Pragma("unroll")                                              \
                for (int nt = 0; nt < 2; ++nt)                                 \
                    acc[mt][nt] = __builtin_amdgcn_mfma_f32_32x32x16_f16(      \
                        AFC[mt][h], BFC[nt][h], acc[mt][nt], 0, 0, 0);         \
        __builtin_amdgcn_s_setprio(0);                                         \
        WAIT_LGKM0();                                                          \
    } while (0)

    // prologue: B(0)->slot0, B(1)->slot1, A(0); drain B(0); read bf(0)
    PV_STAGEB(0);
    PV_STAGEB(1);
    PV_GLOADA(afA, 0);
    WAIT_VM(6);        // drains B(0); leaves B(1)2 + A(0)4
    BARRIER_RAW();
    PV_READB(bfA, 0);

    for (int k = 0; k < 64; k += 2) {
        PV_ITER(k,     afA, bfA, afB, bfB);
        PV_ITER(k + 1, afB, bfB, afA, bfA);
    }

    // C/D 32x32: col = lane&31, row = (reg&3) + 8*(reg>>2) + 4*(lane>>5)
#pragma unroll
    for (int mt = 0; mt < 2; ++mt) {
#pragma unroll
        for (int nt = 0; nt < 2; ++nt) {
            int col = n0 + t.wn + nt * 32 + t.l31;
#pragma unroll
            for (int reg = 0; reg < 16; ++reg) {
                int row = m0 + t.wm + mt * 32 + (reg & 3) + 8 * (reg >> 2) + 4 * t.half;
                size_t gidx = ((size_t)(b * SEQ + row)) * INTER + col;
                float uv = (float)u[gidx];
                u[gidx] = (_Float16)(acc[mt][nt][reg] * uv);
            }
        }
    }
}

// ---------------------------------------------------------------- GEMM2: out = t @ Wo (fp32 out, 32x32 MFMA, read-ahead)
__global__ __launch_bounds__(256) void gemm2_kernel(
    const _Float16* __restrict__ tin, const _Float16* __restrict__ WoT,
    float* __restrict__ out)
{
    __shared__ _Float16 smem[32768];   // 4 slots x 16KB
    TileCtx t = make_ctx();
    const int f = blockIdx.x;
    const int xcd = f & 7, i = f >> 3;
    const int m0 = ((xcd << 3) | (i & 7)) * 128;
    const int n0 = (i >> 3) * 128;

    floatx16 acc[2][2] = {};
    gemm_mainloop_ro32(t, tin + (size_t)m0 * INTER, INTER, WoT + (size_t)n0 * INTER, INTER, INTER, smem, acc);

#pragma unroll
    for (int mt = 0; mt < 2; ++mt) {
#pragma unroll
        for (int nt = 0; nt < 2; ++nt) {
            int col = n0 + t.wn + nt * 32 + t.l31;
#pragma unroll
            for (int reg = 0; reg < 16; ++reg) {
                int row = m0 + t.wm + mt * 32 + (reg & 3) + 8 * (reg >> 2) + 4 * t.half;
                out[(size_t)row * HID + col] = acc[mt][nt][reg];
            }
        }
    }
}

// ---------------------------------------------------------------- launch
extern "C" void kernel_launch(void* const* d_in, const int* in_sizes, int n_in,
                              void* d_out, int out_size, void* d_ws, size_t ws_size,
                              hipStream_t stream) {
    const float* H    = (const float*)d_in[0];
    const float* Wi   = (const float*)d_in[1];
    const float* Wo   = (const float*)d_in[2];
    const float* qg   = (const float*)d_in[3];
    const float* kg   = (const float*)d_in[4];
    const int*   mask = (const int*)d_in[5];
    float* out = (float*)d_out;

    char* base = (char*)d_ws;
    size_t off = 0;
    auto alloc = [&](size_t bytes) { void* p = base + off; off = (off + bytes + 255) & ~(size_t)255; return p; };
    _Float16* Hb   = (_Float16*)alloc((size_t)MROWS * HID * 2);
    _Float16* WiT  = (_Float16*)alloc((size_t)NTOTP * HID * 2);
    _Float16* WoT  = (_Float16*)alloc((size_t)HID * INTER * 2);
    _Float16* u    = (_Float16*)alloc((size_t)MROWS * INTER * 2);
    _Float16* vT   = (_Float16*)alloc((size_t)BATCH * INTER * SEQ * 2);
    _Float16* q    = (_Float16*)alloc((size_t)MROWS * DK * 2);
    _Float16* k    = (_Float16*)alloc((size_t)MROWS * DK * 2);
    _Float16* P    = (_Float16*)alloc((size_t)BATCH * SEQ * SEQ * 2);  // P_frag layout
    float*    scales = (float*)alloc(4 * sizeof(float));

    prep_kernel<<<6724, 256, 0, stream>>>(H, Hb, Wi, WiT, Wo, WoT, mask, scales);
    gemm1_kernel<<<416, 512, 0, stream>>>(Hb, WiT, qg, kg, u, vT, q, k);
    scores_kernel<<<512, 256, 0, stream>>>(q, k, mask, scales, P);
    pv_kernel<<<768, 256, 0, stream>>>(P, vT, u);
    gemm2_kernel<<<384, 256, 0, stream>>>(u, WoT, out);
}

// Round 7
// 296.883 us; speedup vs baseline: 1.0036x; 1.0036x over previous
//
#include <hip/hip_runtime.h>
#include <hip/hip_bf16.h>
#include <math.h>

// Problem constants
#define BATCH 4
#define SEQ   2048
#define HID   768
#define INTER 1536
#define DK    128
#define NTOT  3200      // 2*INTER + DK
#define NTOTP 3328      // padded to 13*256 for 256-wide gemm1 tiles
#define MROWS 8192      // BATCH*SEQ
#define LN512 6.2383246250395075f

typedef _Float16 half8   __attribute__((ext_vector_type(8)));
typedef _Float16 half4   __attribute__((ext_vector_type(4)));
typedef float    floatx4 __attribute__((ext_vector_type(4)));
typedef float    floatx16 __attribute__((ext_vector_type(16)));

typedef const __attribute__((address_space(1))) unsigned int* gas1_t;
typedef __attribute__((address_space(3))) unsigned int* las3_t;

static __device__ __forceinline__ void load16(const _Float16* g, _Float16* l) {
    __builtin_amdgcn_global_load_lds((gas1_t)g, (las3_t)l, 16, 0, 0);
}
#define WAIT_VM(N)    asm volatile("s_waitcnt vmcnt(" #N ")" ::: "memory")
#define WAIT_LGKM0()  asm volatile("s_waitcnt lgkmcnt(0)" ::: "memory")
#define BARRIER_RAW() asm volatile("s_barrier" ::: "memory")
#define GLOAD16(dst, ptr) \
    asm volatile("global_load_dwordx4 %0, %1, off" : "=v"(dst) : "v"(ptr) : "memory")

// ---------------------------------------------------------------- merged prep kernel
__global__ __launch_bounds__(256) void prep_kernel(
    const float* __restrict__ H, _Float16* __restrict__ Hb,
    const float* __restrict__ Wi, _Float16* __restrict__ WiT,
    const float* __restrict__ Wo, _Float16* __restrict__ WoT,
    const int* __restrict__ mask, float* __restrict__ scales)
{
    __shared__ _Float16 tile[32][33];
    __shared__ int sh[256];
    const int bid = blockIdx.x, tid = threadIdx.x;
    if (bid < 3072) {
        const int i = (bid * 256 + tid) * 8;
        float4 a = *reinterpret_cast<const float4*>(H + i);
        float4 b = *reinterpret_cast<const float4*>(H + i + 4);
        half8 h = {(_Float16)a.x, (_Float16)a.y, (_Float16)a.z, (_Float16)a.w,
                   (_Float16)b.x, (_Float16)b.y, (_Float16)b.z, (_Float16)b.w};
        *reinterpret_cast<half8*>(Hb + i) = h;
    } else if (bid < 3072 + 2496) {
        const int l = bid - 3072;
        const int c0 = (l % 104) * 32, r0 = (l / 104) * 32;
        const int tx = tid & 31, ty = tid >> 5;
#pragma unroll
        for (int j = 0; j < 32; j += 8)
            tile[tx][ty + j] = (c0 + tx < NTOT)
                ? (_Float16)Wi[(size_t)(r0 + ty + j) * NTOT + c0 + tx]
                : (_Float16)0.0f;
        __syncthreads();
#pragma unroll
        for (int j = 0; j < 32; j += 8)
            WiT[(size_t)(c0 + ty + j) * HID + r0 + tx] = tile[ty + j][tx];
    } else if (bid < 3072 + 2496 + 1152) {
        const int l = bid - (3072 + 2496);
        const int c0 = (l % 24) * 32, r0 = (l / 24) * 32;
        const int tx = tid & 31, ty = tid >> 5;
#pragma unroll
        for (int j = 0; j < 32; j += 8)
            tile[tx][ty + j] = (_Float16)Wo[(size_t)(r0 + ty + j) * HID + c0 + tx];
        __syncthreads();
#pragma unroll
        for (int j = 0; j < 32; j += 8)
            WoT[(size_t)(c0 + ty + j) * INTER + r0 + tx] = tile[ty + j][tx];
    } else {
        const int b = bid - (3072 + 2496 + 1152);
        int s = 0;
        for (int i = tid; i < SEQ; i += 256) s += mask[b * SEQ + i];
        sh[tid] = s;
        __syncthreads();
        for (int off = 128; off > 0; off >>= 1) {
            if (tid < off) sh[tid] += sh[tid + off];
            __syncthreads();
        }
        if (tid == 0) scales[b] = logf((float)sh[0]) / LN512;
    }
}

// ---------------------------------------------------------------- shared tile ctx (256-thread kernels)
struct TileCtx {
    int tid, wave, lane, quad, l16, l31, half, wm, wn, c0, c1;
};
static __device__ __forceinline__ TileCtx make_ctx() {
    TileCtx t;
    t.tid = threadIdx.x;
    t.wave = t.tid >> 6; t.lane = t.tid & 63;
    t.quad = t.lane >> 4; t.l16 = t.lane & 15;
    t.l31 = t.lane & 31;  t.half = t.lane >> 5;
    t.wm = (t.wave & 1) * 64;
    t.wn = (t.wave >> 1) * 64;
    t.c0 = t.tid;
    t.c1 = t.tid + 256;
    return t;
}

// ================================================================ mainloop LITE32: 32x32x16, occupancy-first (gemm2)
// Single frag set (no ping-pong, -32 VGPR), 3 slots x 16KB, stage-dist 2.
// Per iter: {ds_read frags(k); stage(k+2); vmcnt(4); lgkm0; barrier; MFMA(k)}.
// lgkm0 BEFORE barrier k => reads of slot s complete before the wave crosses
// barrier k; overwrite of that slot (stage at iter k+... after barrier) is safe
// with 3 slots. vm ledger: queue at wait = St(k+1)4 + St(k+2)4 -> VM(4) drains
// St(k+1) (needed next iter); tail VM(0).
static __device__ __forceinline__ void gemm_mainloop_lite32(
    const TileCtx& t,
    const _Float16* __restrict__ Ag, int lda,
    const _Float16* __restrict__ Bg, int ldb,
    int K, _Float16* smem, floatx16 acc[2][2])
{
    const int r0i = t.c0 >> 2, s0 = (((r0i >> 1) ^ (r0i >> 3)) & 3);
    const int r1i = t.c1 >> 2, s1 = (((r1i >> 1) ^ (r1i >> 3)) & 3);
    const _Float16* a0 = Ag + (size_t)r0i * lda + ((t.c0 & 3) ^ s0) * 8;
    const _Float16* a1 = Ag + (size_t)r1i * lda + ((t.c1 & 3) ^ s1) * 8;
    const _Float16* b0 = Bg + (size_t)r0i * ldb + ((t.c0 & 3) ^ s0) * 8;
    const _Float16* b1 = Bg + (size_t)r1i * ldb + ((t.c1 & 3) ^ s1) * 8;
    const int nIter = K >> 5;
    const int fsw = ((t.l31 >> 1) ^ (t.l31 >> 3)) & 3;
    half8 af[2][2], bf[2][2];

#define L32_STAGE(KK) do {                                                     \
        _Float16* ld_ = smem + ((KK) % 3) * 8192 + t.c0 * 8;                   \
        const int ko_ = (KK) << 5;                                             \
        load16(a0 + ko_, ld_);        load16(a1 + ko_, ld_ + 2048);            \
        load16(b0 + ko_, ld_ + 4096); load16(b1 + ko_, ld_ + 6144);            \
    } while (0)

    L32_STAGE(0);
    L32_STAGE(1);
    WAIT_VM(4);        // drains St(0), leaves St(1)
    BARRIER_RAW();

    for (int k = 0; k < nIter; ++k) {
        const _Float16* Ab = smem + (k % 3) * 8192;
        const _Float16* Bb = Ab + 4096;
#pragma unroll
        for (int mt = 0; mt < 2; ++mt)
#pragma unroll
            for (int h = 0; h < 2; ++h)
                af[mt][h] = *reinterpret_cast<const half8*>(
                    Ab + (t.wm + mt * 32 + t.l31) * 32 + (((h * 2 + t.half) ^ fsw) * 8));
#pragma unroll
        for (int nt = 0; nt < 2; ++nt)
#pragma unroll
            for (int h = 0; h < 2; ++h)
                bf[nt][h] = *reinterpret_cast<const half8*>(
                    Bb + (t.wn + nt * 32 + t.l31) * 32 + (((h * 2 + t.half) ^ fsw) * 8));
        if (k + 2 < nIter) L32_STAGE(k + 2);
        if (k + 2 < nIter) { WAIT_VM(4); } else { WAIT_VM(0); }
        WAIT_LGKM0();
        __builtin_amdgcn_sched_barrier(0);
        BARRIER_RAW();
        __builtin_amdgcn_s_setprio(1);
#pragma unroll
        for (int h = 0; h < 2; ++h)
#pragma unroll
            for (int mt = 0; mt < 2; ++mt)
#pragma unroll
                for (int nt = 0; nt < 2; ++nt)
                    acc[mt][nt] = __builtin_amdgcn_mfma_f32_32x32x16_f16(
                        af[mt][h], bf[nt][h], acc[mt][nt], 0, 0, 0);
        __builtin_amdgcn_s_setprio(0);
    }
}

// ---------------------------------------------------------------- GEMM1: silu(H@Wi) -> u, vT, q, k
// R6 read-ahead schedule (unchanged): 256x256 tile, 512 threads, 4 slots,
// distance-3, {stage(t+3); vmcnt; barrier; ds_read frags(t+1); MFMA(t); lgkm0}.
__global__ __launch_bounds__(512, 2) void gemm1_kernel(
    const _Float16* __restrict__ Hb, const _Float16* __restrict__ WiT,
    const float* __restrict__ qg, const float* __restrict__ kg,
    _Float16* __restrict__ u, _Float16* __restrict__ vT,
    _Float16* __restrict__ q, _Float16* __restrict__ k)
{
    __shared__ _Float16 smem[65536];   // 4 slots x 32KB (A 16KB + B 16KB)
    const int tid = threadIdx.x;
    const int lane = tid & 63, wave = tid >> 6;
    const int quad = lane >> 4, l16 = lane & 15;
    const int wm = wave >> 2, wn = wave & 3;          // 2M x 4N waves

    const int f = blockIdx.x;
    const int xcd = f & 7, i = f >> 3;                // i: 0..51
    const int m0 = (xcd * 4 + (i & 3)) * 256;
    const int ntile = i >> 2;                         // 0..12
    const int n0 = ntile * 256;

    const _Float16* Ag = Hb  + (size_t)m0 * HID;
    const _Float16* Bg = WiT + (size_t)n0 * HID;

    const int rA = tid >> 2;
    const int csw = ((tid & 3) ^ ((rA >> 1) & 3)) * 8;
    const _Float16* pa0 = Ag + (size_t)rA * HID + csw;
    const _Float16* pa1 = pa0 + (size_t)128 * HID;
    const _Float16* pb0 = Bg + (size_t)rA * HID + csw;
    const _Float16* pb1 = pb0 + (size_t)128 * HID;

    const int sw8 = (l16 >> 1) & 3;
    const int qs  = (quad ^ sw8) * 8;
    const int aoff = (wm * 128 + l16) * 32 + qs;
    const int boff = 8192 + (wn * 64 + l16) * 32 + qs;

    floatx4 acc[8][4] = {};
    half8 pa_[8], pb_[4], qa_[8], qb_[4];   // ping-pong frag sets

    const int nKt = HID / 32;   // 24

#define G1_STAGE(T) do {                                                       \
        _Float16* ld_ = smem + ((T) & 3) * 16384 + tid * 8;                    \
        const int ko_ = (T) << 5;                                              \
        load16(pa0 + ko_, ld_);        load16(pa1 + ko_, ld_ + 4096);          \
        load16(pb0 + ko_, ld_ + 8192); load16(pb1 + ko_, ld_ + 12288);         \
    } while (0)

#define G1_READ(AF, BF, SLOT) do {                                             \
        const _Float16* sl_ = smem + (SLOT) * 16384;                           \
        _Pragma("unroll")                                                      \
        for (int mt = 0; mt < 8; ++mt)                                         \
            AF[mt] = *reinterpret_cast<const half8*>(sl_ + aoff + mt * 512);   \
        _Pragma("unroll")                                                      \
        for (int nt = 0; nt < 4; ++nt)                                         \
            BF[nt] = *reinterpret_cast<const half8*>(sl_ + boff + nt * 512);   \
    } while (0)

#define G1_ITER(T, AFC, BFC, AFN, BFN) do {                                    \
        if ((T) + 3 < nKt) G1_STAGE((T) + 3);                                  \
        if ((T) + 3 < nKt)      { WAIT_VM(8); }                                \
        else if ((T) + 2 < nKt) { WAIT_VM(4); }                                \
        else                    { WAIT_VM(0); }                                \
        __builtin_amdgcn_sched_barrier(0);                                     \
        BARRIER_RAW();                                                         \
        if ((T) + 1 < nKt) G1_READ(AFN, BFN, ((T) + 1) & 3);                   \
        __builtin_amdgcn_s_setprio(1);                                         \
        _Pragma("unroll")                                                      \
        for (int mt = 0; mt < 8; ++mt)                                         \
            _Pragma("unroll")                                                  \
            for (int nt = 0; nt < 4; ++nt)                                     \
                acc[mt][nt] = __builtin_amdgcn_mfma_f32_16x16x32_f16(          \
                    AFC[mt], BFC[nt], acc[mt][nt], 0, 0, 0);                   \
        __builtin_amdgcn_s_setprio(0);                                         \
        WAIT_LGKM0();                                                          \
    } while (0)

    G1_STAGE(0); G1_STAGE(1); G1_STAGE(2);
    WAIT_VM(8);
    BARRIER_RAW();
    G1_READ(pa_, pb_, 0);

    for (int t = 0; t < nKt; t += 2) {
        G1_ITER(t,     pa_, pb_, qa_, qb_);
        G1_ITER(t + 1, qa_, qb_, pa_, pb_);
    }
    __syncthreads();

    // ---------------- epilogue: silu + region-specific stores
    if (ntile < 6) {
#pragma unroll
        for (int mt = 0; mt < 8; ++mt) {
#pragma unroll
            for (int nt = 0; nt < 4; ++nt) {
                const int col = n0 + wn * 64 + nt * 16 + l16;
#pragma unroll
                for (int i2 = 0; i2 < 4; ++i2) {
                    const int row = m0 + wm * 128 + mt * 16 + quad * 4 + i2;
                    float x = acc[mt][nt][i2];
                    float y = x / (1.0f + __expf(-x));
                    u[(size_t)row * INTER + col] = (_Float16)y;
                }
            }
        }
    } else if (ntile < 12) {
        const int bb = m0 >> 11, sloc = m0 & (SEQ - 1), cI = n0 - INTER;
#pragma unroll
        for (int mt = 0; mt < 8; ++mt) {
#pragma unroll
            for (int nt = 0; nt < 4; ++nt) {
                const int cl  = wn * 64 + nt * 16 + l16;
                const int rl0 = wm * 128 + mt * 16 + quad * 4;
                half4 pk;
#pragma unroll
                for (int i2 = 0; i2 < 4; ++i2) {
                    float x = acc[mt][nt][i2];
                    pk[i2] = (_Float16)(x / (1.0f + __expf(-x)));
                }
                *reinterpret_cast<half4*>(smem + cl * 256 + (rl0 ^ ((cl & 31) << 3))) = pk;
            }
        }
        __syncthreads();
#pragma unroll
        for (int p = 0; p < 16; ++p) {
            const int chunk = p * 512 + tid;
            const int cl = chunk >> 5, scn = chunk & 31;
            half8 v = *reinterpret_cast<const half8*>(smem + cl * 256 + ((scn ^ (cl & 31)) << 3));
            *reinterpret_cast<half8*>(vT + ((size_t)bb * INTER + cI + cl) * SEQ + sloc + scn * 8) = v;
        }
    } else {
        if (wn < 2) {
#pragma unroll
            for (int mt = 0; mt < 8; ++mt) {
#pragma unroll
                for (int nt = 0; nt < 4; ++nt) {
                    const int cq = wn * 64 + nt * 16 + l16;
                    const float qgv = qg[cq], kgv = kg[cq];
#pragma unroll
                    for (int i2 = 0; i2 < 4; ++i2) {
                        const int row = m0 + wm * 128 + mt * 16 + quad * 4 + i2;
                        float x = acc[mt][nt][i2];
                        float y = x / (1.0f + __expf(-x));
                        q[(size_t)row * DK + cq] = (_Float16)(y * qgv);
                        k[(size_t)row * DK + cq] = (_Float16)(y * kgv);
                    }
                }
            }
        }
    }
}

// ---------------------------------------------------------------- scores + softmax -> P_frag (f16)
__global__ __launch_bounds__(256) void scores_kernel(
    const _Float16* __restrict__ q, const _Float16* __restrict__ k,
    const int* __restrict__ mask, const float* __restrict__ scales,
    _Float16* __restrict__ P)
{
    __shared__ _Float16 ps[16 * 2056];
    __shared__ float redmax[4][16];
    __shared__ float redsum[4][16];
    const int f = blockIdx.x;
    const int xcd = f & 7, i = f >> 3;          // i: 0..63
    const int b = xcd >> 1;
    const int m0 = ((xcd & 1) * 64 + i) * 16;
    const int tid = threadIdx.x;
    const int wave = tid >> 6, lane = tid & 63, quad = lane >> 4, l16 = lane & 15;
    const float scale = scales[b];

    half8 aq[4];
    const _Float16* qrow = q + (b * SEQ + m0 + l16) * DK + quad * 8;
#pragma unroll
    for (int kk = 0; kk < 4; ++kk) aq[kk] = *reinterpret_cast<const half8*>(qrow + kk * 32);

    floatx4 sc[32];
#pragma unroll
    for (int nt = 0; nt < 32; ++nt) {
        int n0 = nt * 64 + wave * 16;
        const _Float16* krow = k + (b * SEQ + n0 + l16) * DK + quad * 8;
        floatx4 acc = {};
#pragma unroll
        for (int kk = 0; kk < 4; ++kk) {
            half8 bq = *reinterpret_cast<const half8*>(krow + kk * 32);
            acc = __builtin_amdgcn_mfma_f32_16x16x32_f16(aq[kk], bq, acc, 0, 0, 0);
        }
        sc[nt] = acc;
    }

    const float rs = 0.08838834764831845f * scale;
    const float mval = -1e12f * scale;
    float rmax[4] = {-3.4e38f, -3.4e38f, -3.4e38f, -3.4e38f};
#pragma unroll
    for (int nt = 0; nt < 32; ++nt) {
        int ncol = nt * 64 + wave * 16 + l16;
        bool mok = mask[b * SEQ + ncol] != 0;
#pragma unroll
        for (int i2 = 0; i2 < 4; ++i2) {
            float s = mok ? sc[nt][i2] * rs : mval;
            sc[nt][i2] = s;
            rmax[i2] = fmaxf(rmax[i2], s);
        }
    }
#pragma unroll
    for (int i2 = 0; i2 < 4; ++i2) {
#pragma unroll
        for (int off = 1; off < 16; off <<= 1)
            rmax[i2] = fmaxf(rmax[i2], __shfl_xor(rmax[i2], off, 64));
    }
    if (l16 == 0) {
#pragma unroll
        for (int i2 = 0; i2 < 4; ++i2) redmax[wave][quad * 4 + i2] = rmax[i2];
    }
    __syncthreads();
#pragma unroll
    for (int i2 = 0; i2 < 4; ++i2) {
        int r = quad * 4 + i2;
        rmax[i2] = fmaxf(fmaxf(redmax[0][r], redmax[1][r]), fmaxf(redmax[2][r], redmax[3][r]));
    }
    float rsum[4] = {0.f, 0.f, 0.f, 0.f};
#pragma unroll
    for (int nt = 0; nt < 32; ++nt) {
#pragma unroll
        for (int i2 = 0; i2 < 4; ++i2) {
            float e = __expf(sc[nt][i2] - rmax[i2]);
            sc[nt][i2] = e;
            rsum[i2] += e;
        }
    }
#pragma unroll
    for (int i2 = 0; i2 < 4; ++i2) {
#pragma unroll
        for (int off = 1; off < 16; off <<= 1) rsum[i2] += __shfl_xor(rsum[i2], off, 64);
    }
    if (l16 == 0) {
#pragma unroll
        for (int i2 = 0; i2 < 4; ++i2) redsum[wave][quad * 4 + i2] = rsum[i2];
    }
    __syncthreads();
#pragma unroll
    for (int i2 = 0; i2 < 4; ++i2) {
        int r = quad * 4 + i2;
        float tot = redsum[0][r] + redsum[1][r] + redsum[2][r] + redsum[3][r];
        float inv = 1.0f / tot;
#pragma unroll
        for (int nt = 0; nt < 32; ++nt) {
            int ncol = nt * 64 + wave * 16 + l16;
            ps[r * 2056 + ncol] = (_Float16)(sc[nt][i2] * inv);
        }
    }
    __syncthreads();
    _Float16* Pfb = P + (size_t)b * SEQ * SEQ;
#pragma unroll
    for (int p = 0; p < 16; ++p) {
        const int chunk = p * 256 + tid;
        const int row = chunk & 15, c8 = chunk >> 4;
        half8 v = *reinterpret_cast<const half8*>(ps + row * 2056 + c8 * 8);
        *reinterpret_cast<half8*>(Pfb + ((size_t)c8 * SEQ + m0 + row) * 8) = v;
    }
}

// ---------------------------------------------------------------- PV: u <- u .* (P @ v)
// R7: occupancy-first. Single frag sets (af, bf), __launch_bounds__(256,3) ->
// 3 blocks/CU. A (P_frag) global->VGPR loaded right after MFMA consumed it;
// B (vT) in 4 LDS slots x 8KB. Per iter: {ds_read bf(k); stageB(k+2); VM(2);
// lgkm0; barrier; MFMA(k); gloadA(k+1)}. vm ledger: queue at wait =
// Bst(k+1)2 + A(k)4 + Bst(k+2)2 -> VM(2) drains Bst(k+1)+A(k).
__global__ __launch_bounds__(256, 3) void pv_kernel(
    const _Float16* __restrict__ Pf, const _Float16* __restrict__ vT,
    _Float16* __restrict__ u)
{
    __shared__ _Float16 smem[16384];   // 4 slots x 8KB (B only)
    TileCtx t = make_ctx();
    const int f = blockIdx.x;
    const int xcd = f & 7, i = f >> 3;
    const int b = i / 24, j = i % 24;
    const int m0 = (xcd * 2 + (j & 1)) * 128;
    const int n0 = (j >> 1) * 128;
    const _Float16* Pfb = Pf + (size_t)b * SEQ * SEQ;   // [256 chunks][2048 rows][8]
    const _Float16* vTb = vT + (size_t)b * INTER * SEQ;

    const int r0i = t.c0 >> 2, s0 = (((r0i >> 1) ^ (r0i >> 3)) & 3);
    const int r1i = t.c1 >> 2, s1 = (((r1i >> 1) ^ (r1i >> 3)) & 3);
    const _Float16* b0 = vTb + (size_t)(n0 + r0i) * SEQ + ((t.c0 & 3) ^ s0) * 8;
    const _Float16* b1 = vTb + (size_t)(n0 + r1i) * SEQ + ((t.c1 & 3) ^ s1) * 8;
    const int fsw = ((t.l31 >> 1) ^ (t.l31 >> 3)) & 3;

    const _Float16* pA0 = Pfb + (size_t)t.half * (SEQ * 8)
                        + (size_t)(m0 + t.wm + t.l31) * 8;
    const _Float16* pA1 = pA0 + 32 * 8;

    floatx16 acc[2][2] = {};
    half8 af[2][2], bf[2][2];

#define PV_GLOADA(K) do {                                                      \
        const size_t co_ = (size_t)(K) * 4 * (SEQ * 8);                        \
        GLOAD16(af[0][0], pA0 + co_);                                          \
        GLOAD16(af[0][1], pA0 + co_ + 2 * (SEQ * 8));                          \
        GLOAD16(af[1][0], pA1 + co_);                                          \
        GLOAD16(af[1][1], pA1 + co_ + 2 * (SEQ * 8));                          \
    } while (0)

#define PV_STAGEB(K) do {                                                      \
        _Float16* ld_ = smem + ((K) & 3) * 4096 + t.c0 * 8;                    \
        const int ko_ = (K) << 5;                                              \
        load16(b0 + ko_, ld_);                                                 \
        load16(b1 + ko_, ld_ + 2048);                                          \
    } while (0)

    // prologue: B(0)->slot0, B(1)->slot1, A(0); drain B(0),B(1)
    PV_STAGEB(0);
    PV_STAGEB(1);
    PV_GLOADA(0);
    WAIT_VM(4);        // drains Bst(0),Bst(1); leaves A(0)4
    BARRIER_RAW();

    for (int k = 0; k < 64; ++k) {
        const _Float16* Bb = smem + (k & 3) * 4096;
#pragma unroll
        for (int nt = 0; nt < 2; ++nt)
#pragma unroll
            for (int h = 0; h < 2; ++h)
                bf[nt][h] = *reinterpret_cast<const half8*>(
                    Bb + (t.wn + nt * 32 + t.l31) * 32 + (((h * 2 + t.half) ^ fsw) * 8));
        if (k + 2 < 64) PV_STAGEB(k + 2);
        if (k <= 61) { WAIT_VM(2); } else { WAIT_VM(0); }
        WAIT_LGKM0();
        __builtin_amdgcn_sched_barrier(0);
        BARRIER_RAW();
        __builtin_amdgcn_s_setprio(1);
#pragma unroll
        for (int h = 0; h < 2; ++h)
#pragma unroll
            for (int mt = 0; mt < 2; ++mt)
#pragma unroll
                for (int nt = 0; nt < 2; ++nt)
                    acc[mt][nt] = __builtin_amdgcn_mfma_f32_32x32x16_f16(
                        af[mt][h], bf[nt][h], acc[mt][nt], 0, 0, 0);
        __builtin_amdgcn_s_setprio(0);
        if (k + 1 < 64) PV_GLOADA(k + 1);
    }

    // C/D 32x32: col = lane&31, row = (reg&3) + 8*(reg>>2) + 4*(lane>>5)
#pragma unroll
    for (int mt = 0; mt < 2; ++mt) {
#pragma unroll
        for (int nt = 0; nt < 2; ++nt) {
            int col = n0 + t.wn + nt * 32 + t.l31;
#pragma unroll
            for (int reg = 0; reg < 16; ++reg) {
                int row = m0 + t.wm + mt * 32 + (reg & 3) + 8 * (reg >> 2) + 4 * t.half;
                size_t gidx = ((size_t)(b * SEQ + row)) * INTER + col;
                float uv = (float)u[gidx];
                u[gidx] = (_Float16)(acc[mt][nt][reg] * uv);
            }
        }
    }
}

// ---------------------------------------------------------------- GEMM2: out = t @ Wo (fp32 out, 32x32 MFMA, lite)
__global__ __launch_bounds__(256, 3) void gemm2_kernel(
    const _Float16* __restrict__ tin, const _Float16* __restrict__ WoT,
    float* __restrict__ out)
{
    __shared__ _Float16 smem[24576];   // 3 slots x 16KB
    TileCtx t = make_ctx();
    const int f = blockIdx.x;
    const int xcd = f & 7, i = f >> 3;
    const int m0 = ((xcd << 3) | (i & 7)) * 128;
    const int n0 = (i >> 3) * 128;

    floatx16 acc[2][2] = {};
    gemm_mainloop_lite32(t, tin + (size_t)m0 * INTER, INTER, WoT + (size_t)n0 * INTER, INTER, INTER, smem, acc);

#pragma unroll
    for (int mt = 0; mt < 2; ++mt) {
#pragma unroll
        for (int nt = 0; nt < 2; ++nt) {
            int col = n0 + t.wn + nt * 32 + t.l31;
#pragma unroll
            for (int reg = 0; reg < 16; ++reg) {
                int row = m0 + t.wm + mt * 32 + (reg & 3) + 8 * (reg >> 2) + 4 * t.half;
                out[(size_t)row * HID + col] = acc[mt][nt][reg];
            }
        }
    }
}

// ---------------------------------------------------------------- launch
extern "C" void kernel_launch(void* const* d_in, const int* in_sizes, int n_in,
                              void* d_out, int out_size, void* d_ws, size_t ws_size,
                              hipStream_t stream) {
    const float* H    = (const float*)d_in[0];
    const float* Wi   = (const float*)d_in[1];
    const float* Wo   = (const float*)d_in[2];
    const float* qg   = (const float*)d_in[3];
    const float* kg   = (const float*)d_in[4];
    const int*   mask = (const int*)d_in[5];
    float* out = (float*)d_out;

    char* base = (char*)d_ws;
    size_t off = 0;
    auto alloc = [&](size_t bytes) { void* p = base + off; off = (off + bytes + 255) & ~(size_t)255; return p; };
    _Float16* Hb   = (_Float16*)alloc((size_t)MROWS * HID * 2);
    _Float16* WiT  = (_Float16*)alloc((size_t)NTOTP * HID * 2);
    _Float16* WoT  = (_Float16*)alloc((size_t)HID * INTER * 2);
    _Float16* u    = (_Float16*)alloc((size_t)MROWS * INTER * 2);
    _Float16* vT   = (_Float16*)alloc((size_t)BATCH * INTER * SEQ * 2);
    _Float16* q    = (_Float16*)alloc((size_t)MROWS * DK * 2);
    _Float16* k    = (_Float16*)alloc((size_t)MROWS * DK * 2);
    _Float16* P    = (_Float16*)alloc((size_t)BATCH * SEQ * SEQ * 2);  // P_frag layout
    float*    scales = (float*)alloc(4 * sizeof(float));

    prep_kernel<<<6724, 256, 0, stream>>>(H, Hb, Wi, WiT, Wo, WoT, mask, scales);
    gemm1_kernel<<<416, 512, 0, stream>>>(Hb, WiT, qg, kg, u, vT, q, k);
    scores_kernel<<<512, 256, 0, stream>>>(q, k, mask, scales, P);
    pv_kernel<<<768, 256, 0, stream>>>(P, vT, u);
    gemm2_kernel<<<384, 256, 0, stream>>>(u, WoT, out);
}